// Round 5
// baseline (2257.073 us; speedup 1.0000x reference)
//
#include <hip/hip_runtime.h>

#define HID  64
#define SEQT 1024

typedef float v2f __attribute__((ext_vector_type(2)));
typedef float v4f __attribute__((ext_vector_type(4)));

__device__ __forceinline__ float rcpf(float x){ return __builtin_amdgcn_rcpf(x); }
__device__ __forceinline__ float sigm(float x){ return rcpf(1.0f + __expf(-x)); }
__device__ __forceinline__ float tanh_fast(float x){
    // 1 - 2/(e^{2x}+1); correct saturation at +-inf
    return 1.0f - 2.0f * rcpf(__expf(2.0f * x) + 1.0f);
}
__device__ __forceinline__ v2f pkfma(v2f a, v2f b, v2f c){
    return __builtin_elementwise_fma(a, b, c);      // -> v_pk_fma_f32
}

// Round-1 structure (proven clean regalloc + 66% busy) with the two fixes:
//  * __launch_bounds__(256,1): 512-reg budget -> all 192 weight floats live in
//    ARCH VGPRs (demand ~230), killing the v_accvgpr_read-per-weight-use tax
//    that round 1 (cap 256 -> 128 arch + AGPR) paid ~230 instr/step for.
//    230 < 256 still allows 2 waves/SIMD co-residency.
//  * v_pk_fma_f32: 192 scalar FMA/step -> 96 packed.
// One block = one batch element; wave w = gate type, lane j = unit; h1/h2
// per-wave LDS replicas (broadcast b128 reads, own-replica writes need no
// barrier); 2 barriers/step (after gates0, after gates1).
__global__ __launch_bounds__(256, 1)
void lstm2_arch(const float* __restrict__ x,
                const float* __restrict__ W_ih0, const float* __restrict__ W_hh0,
                const float* __restrict__ b_ih0, const float* __restrict__ b_hh0,
                const float* __restrict__ W_ih1, const float* __restrict__ W_hh1,
                const float* __restrict__ b_ih1, const float* __restrict__ b_hh1,
                const float* __restrict__ fc1_w, const float* __restrict__ fc1_b,
                const float* __restrict__ fc2_w, const float* __restrict__ fc2_b,
                float* __restrict__ out, int batch)
{
    const int b   = blockIdx.x;
    if (b >= batch) return;
    const int tid = threadIdx.x;
    const int w   = tid >> 6;     // wave = gate type (0:i 1:f 2:g 3:o)
    const int j   = tid & 63;     // lane = unit
    const int g   = tid;          // gate row 0..255

    __shared__ float gates0[256];
    __shared__ float gates1[256];
    __shared__ __align__(16) float h1buf[4][HID];   // per-wave replicas
    __shared__ __align__(16) float h2buf[4][HID];

    // ---- register-resident weight rows (96 v2f = 192 arch VGPRs) ----
    v2f whh0[32], wih1[32], whh1[32];
    {
        const v2f* r0 = (const v2f*)(W_hh0 + g * HID);
        const v2f* r1 = (const v2f*)(W_ih1 + g * HID);
        const v2f* r2 = (const v2f*)(W_hh1 + g * HID);
        #pragma unroll
        for (int q = 0; q < 32; ++q) { whh0[q] = r0[q]; wih1[q] = r1[q]; whh1[q] = r2[q]; }
        #pragma unroll
        for (int q = 0; q < 32; ++q) {
            asm volatile("" : "+v"(whh0[q]));        // pin live; forbid remat/reload
            asm volatile("" : "+v"(wih1[q]));
            asm volatile("" : "+v"(whh1[q]));
        }
    }
    const float wih0g = W_ih0[g];                    // INPUT_SIZE == 1
    const float bias0 = b_ih0[g] + b_hh0[g];
    const float bias1 = b_ih1[g] + b_hh1[g];

    float c1 = 0.0f, c2 = 0.0f;
    h1buf[w][j] = 0.0f;
    h2buf[w][j] = 0.0f;
    __syncthreads();

    const float* __restrict__ xrow = x + (size_t)b * SEQT;
    float* __restrict__ h1w = h1buf[w];
    float* __restrict__ h2w = h2buf[w];
    const v4f* __restrict__ h1v = (const v4f*)h1w;
    const v4f* __restrict__ h2v = (const v4f*)h2w;

    for (int t0 = 0; t0 < SEQT; t0 += 64) {
        const float xchunk = xrow[t0 + j];           // 64-step x prefetch
        #pragma unroll 1
        for (int tt = 0; tt < 64; ++tt) {
            const float xt = __shfl(xchunk, tt);

            // ---------- layer 0: 16 broadcast b128 reads, 32 pk ----------
            v2f a0 = {0.f,0.f}, a1 = {0.f,0.f};
            #pragma unroll
            for (int q = 0; q < 16; ++q) {
                v4f h = h1v[q];
                a0 = pkfma((v2f){h.x, h.y}, whh0[2*q],     a0);
                a1 = pkfma((v2f){h.z, h.w}, whh0[2*q + 1], a1);
            }
            v2f s = a0 + a1;
            float pre0 = fmaf(xt, wih0g, bias0) + (s.x + s.y);
            gates0[g] = (w == 2) ? tanh_fast(pre0) : sigm(pre0);
            __syncthreads();

            // ---------- layer 0 cell update (redundant per wave) ----------
            {
                float i0 = gates0[j],        f0 = gates0[64 + j];
                float g0 = gates0[128 + j],  o0 = gates0[192 + j];
                c1 = fmaf(f0, c1, i0 * g0);
                h1w[j] = o0 * tanh_fast(c1);         // own replica: no barrier
            }

            // ---------- layer 1: 32 broadcast b128 reads, 64 pk ----------
            v2f b0 = {0.f,0.f}, b1v2 = {0.f,0.f}, b2 = {0.f,0.f}, b3 = {0.f,0.f};
            #pragma unroll
            for (int q = 0; q < 16; ++q) {
                v4f u = h1v[q], v = h2v[q];
                b0   = pkfma((v2f){u.x, u.y}, wih1[2*q],     b0);
                b1v2 = pkfma((v2f){u.z, u.w}, wih1[2*q + 1], b1v2);
                b2   = pkfma((v2f){v.x, v.y}, whh1[2*q],     b2);
                b3   = pkfma((v2f){v.z, v.w}, whh1[2*q + 1], b3);
            }
            v2f sb = (b0 + b1v2) + (b2 + b3);
            float pre1 = bias1 + (sb.x + sb.y);
            gates1[g] = (w == 2) ? tanh_fast(pre1) : sigm(pre1);
            __syncthreads();

            // ---------- layer 1 cell update ----------
            {
                float i1 = gates1[j],        f1 = gates1[64 + j];
                float g1 = gates1[128 + j],  o1 = gates1[192 + j];
                c2 = fmaf(f1, c2, i1 * g1);
                h2w[j] = o1 * tanh_fast(c2);
            }
        }
    }

    // ---------- FC head ----------
    if (w == 0) {
        float z = 0.0f;
        if (j < 32) {
            float acc = fc1_b[j];
            #pragma unroll
            for (int k = 0; k < HID; ++k)
                acc = fmaf(h2w[k], fc1_w[j * HID + k], acc);
            z = fmaxf(acc, 0.0f) * fc2_w[j];
        }
        #pragma unroll
        for (int off = 32; off > 0; off >>= 1) z += __shfl_xor(z, off);
        if (j == 0) out[b] = z + fc2_b[0];
    }
}

extern "C" void kernel_launch(void* const* d_in, const int* in_sizes, int n_in,
                              void* d_out, int out_size, void* d_ws, size_t ws_size,
                              hipStream_t stream) {
    const float* x     = (const float*)d_in[0];
    const float* W_ih0 = (const float*)d_in[1];
    const float* W_hh0 = (const float*)d_in[2];
    const float* b_ih0 = (const float*)d_in[3];
    const float* b_hh0 = (const float*)d_in[4];
    const float* W_ih1 = (const float*)d_in[5];
    const float* W_hh1 = (const float*)d_in[6];
    const float* b_ih1 = (const float*)d_in[7];
    const float* b_hh1 = (const float*)d_in[8];
    const float* fc1_w = (const float*)d_in[9];
    const float* fc1_b = (const float*)d_in[10];
    const float* fc2_w = (const float*)d_in[11];
    const float* fc2_b = (const float*)d_in[12];
    float* out = (float*)d_out;

    const int batch = in_sizes[0] / SEQT;   // 1024
    dim3 grid(batch), block(256);
    hipLaunchKernelGGL(lstm2_arch, grid, block, 0, stream,
                       x, W_ih0, W_hh0, b_ih0, b_hh0,
                       W_ih1, W_hh1, b_ih1, b_hh1,
                       fc1_w, fc1_b, fc2_w, fc2_b, out, batch);
}

// Round 6
// 1199.325 us; speedup vs baseline: 1.8820x; 1.8820x over previous
//
#include <hip/hip_runtime.h>

#define HID  64
#define SEQT 1024
#define NB   4

typedef _Float16 h8 __attribute__((ext_vector_type(8)));
typedef float    f4 __attribute__((ext_vector_type(4)));

__device__ __forceinline__ float rcpf(float x){ return __builtin_amdgcn_rcpf(x); }
__device__ __forceinline__ float sigm(float x){ return rcpf(1.0f + __expf(-x)); }
__device__ __forceinline__ float tanh_fast(float x){
    // 1 - 2/(e^{2x}+1); correct saturation at +-inf
    return 1.0f - 2.0f * rcpf(__expf(2.0f * x) + 1.0f);
}

#define MFMA16(A,B,C) __builtin_amdgcn_mfma_f32_16x16x32_f16((A),(B),(C),0,0,0)

// split fp32 -> f16 hi + f16 lo (exact residual; combined ~2^-24 relative)
__device__ __forceinline__ void split8(const float* __restrict__ p, h8& hi, h8& lo) {
    float4 u = *(const float4*)p;
    float4 v = *(const float4*)(p + 4);
    float vv[8] = {u.x, u.y, u.z, u.w, v.x, v.y, v.z, v.w};
    #pragma unroll
    for (int e = 0; e < 8; ++e) {
        _Float16 h = (_Float16)vv[e];
        hi[e] = h;
        lo[e] = (_Float16)(vv[e] - (float)h);
    }
}

// Block = 4 batch elements, 256 threads = 4 waves. Gates via MFMA 16x16x32 f16
// (3-term hi/lo split ~= fp32 exact). Wave w owns M-tiles 4w..4w+3 = gate type w.
// A-frags (weights, 48 frags = 192 regs) are loop-invariant -> AGPRs, read by
// MFMA directly (no move tax). B-frags (h hi/lo) rebuilt per step from LDS.
// C/D layout (m89-verified): col=lane&15, row=(lane>>4)*4+reg.
// A/B k-index built with the SAME formula k = ks*32 + (lane>>4)*8 + e on both
// sides -> any hw k-permutation cancels in the contraction.
// Cell phase: thread t = (unit j = t&63, batch b = t>>6); wave == batch.
__global__ __launch_bounds__(256, 1)
void lstm2_mfma(const float* __restrict__ x,
                const float* __restrict__ W_ih0, const float* __restrict__ W_hh0,
                const float* __restrict__ b_ih0, const float* __restrict__ b_hh0,
                const float* __restrict__ W_ih1, const float* __restrict__ W_hh1,
                const float* __restrict__ b_ih1, const float* __restrict__ b_hh1,
                const float* __restrict__ fc1_w, const float* __restrict__ fc1_b,
                const float* __restrict__ fc2_w, const float* __restrict__ fc2_b,
                float* __restrict__ out, int nblk)
{
    const int blk = blockIdx.x;
    if (blk >= nblk) return;
    const int tid = threadIdx.x;
    const int w   = tid >> 6;          // wave id; == batch for cell phase
    const int l   = tid & 63;          // lane
    const int r16 = l & 15;            // MFMA row / output col select
    const int g4  = l >> 4;            // k-subgroup
    const int cc  = r16 & 3;           // broadcast col (pad lanes read col&3)
    const int j   = l;                 // cell unit
    const int B0  = blk * NB;

    // ---------------- LDS ----------------
    #define HSTR 80                              // halves; 160B rows: 4-frag reads conflict-free via broadcast
    __shared__ __align__(16) _Float16 h1h[16][HSTR], h1l[16][HSTR];
    __shared__ __align__(16) _Float16 h2h[16][HSTR], h2l[16][HSTR];
    __shared__ __align__(16) float G[NB][260];   // pre-activations, reused L0/L1
    __shared__ __align__(16) float xl[64][8];    // x chunk [t&63][batch]
    __shared__ __align__(16) float h2f[NB][64];  // final h2 (fp32) for FC head

    // ---------------- A-fragments: weights, hi/lo f16 ----------------
    h8 aL0[4][2][2];     // [tile][kstep][hi/lo]  W_hh0
    h8 aL1[4][4][2];     // kstep 0,1: W_ih1 ; kstep 2,3: W_hh1
    #pragma unroll
    for (int tt = 0; tt < 4; ++tt) {
        const int row = 64 * w + tt * 16 + r16;
        #pragma unroll
        for (int ks = 0; ks < 2; ++ks)
            split8(W_hh0 + row * HID + ks * 32 + g4 * 8, aL0[tt][ks][0], aL0[tt][ks][1]);
        #pragma unroll
        for (int ks = 0; ks < 2; ++ks)
            split8(W_ih1 + row * HID + ks * 32 + g4 * 8, aL1[tt][ks][0], aL1[tt][ks][1]);
        #pragma unroll
        for (int ks = 0; ks < 2; ++ks)
            split8(W_hh1 + row * HID + ks * 32 + g4 * 8, aL1[tt][2 + ks][0], aL1[tt][2 + ks][1]);
    }

    // ---------------- cell-thread constants ----------------
    float bias0v[4], bias1v[4], wih0v[4];
    #pragma unroll
    for (int q = 0; q < 4; ++q) {
        const int row = j + 64 * q;
        bias0v[q] = b_ih0[row] + b_hh0[row];
        bias1v[q] = b_ih1[row] + b_hh1[row];
        wih0v[q]  = W_ih0[row];
    }

    // ---------------- init LDS ----------------
    for (int q = tid; q < 16 * HSTR / 2; q += 256) {   // 640 ints per array
        ((int*)h1h)[q] = 0; ((int*)h1l)[q] = 0;
        ((int*)h2h)[q] = 0; ((int*)h2l)[q] = 0;
    }
    xl[tid >> 2][tid & 3] = x[(size_t)(B0 + (tid & 3)) * SEQT + (tid >> 2)];
    float c1 = 0.0f, c2 = 0.0f;
    __syncthreads();

    const f4 z4 = {0.f, 0.f, 0.f, 0.f};
    h8 bh1h[2], bh1l[2], bh2h[2], bh2l[2];
    #pragma unroll
    for (int ks = 0; ks < 2; ++ks) {               // h1(-1) = 0
        bh1h[ks] = *(const h8*)&h1h[cc][ks * 32 + g4 * 8];
        bh1l[ks] = *(const h8*)&h1l[cc][ks * 32 + g4 * 8];
    }

    #pragma unroll 1
    for (int t = 0; t < SEQT; ++t) {
        // ---- B-frags for h2(t-1) ----
        #pragma unroll
        for (int ks = 0; ks < 2; ++ks) {
            bh2h[ks] = *(const h8*)&h2h[cc][ks * 32 + g4 * 8];
            bh2l[ks] = *(const h8*)&h2l[cc][ks * 32 + g4 * 8];
        }

        // ---- L0 MFMA: G0 = Whh0 * h1(t-1), 6 mfma per tile ----
        {
            f4 acc[4];
            #pragma unroll
            for (int tt = 0; tt < 4; ++tt) acc[tt] = MFMA16(aL0[tt][0][0], bh1h[0], z4);
            #pragma unroll
            for (int tt = 0; tt < 4; ++tt) acc[tt] = MFMA16(aL0[tt][0][1], bh1h[0], acc[tt]);
            #pragma unroll
            for (int tt = 0; tt < 4; ++tt) acc[tt] = MFMA16(aL0[tt][0][0], bh1l[0], acc[tt]);
            #pragma unroll
            for (int tt = 0; tt < 4; ++tt) acc[tt] = MFMA16(aL0[tt][1][0], bh1h[1], acc[tt]);
            #pragma unroll
            for (int tt = 0; tt < 4; ++tt) acc[tt] = MFMA16(aL0[tt][1][1], bh1h[1], acc[tt]);
            #pragma unroll
            for (int tt = 0; tt < 4; ++tt) acc[tt] = MFMA16(aL0[tt][1][0], bh1l[1], acc[tt]);
            if (r16 < NB) {
                #pragma unroll
                for (int tt = 0; tt < 4; ++tt)
                    *(f4*)&G[r16][64 * w + tt * 16 + g4 * 4] = acc[tt];
            }
        }
        __syncthreads();                                        // A: preact0 ready

        // ---- cell 0: thread (j, b=w) ----
        {
            const float xt = xl[t & 63][w];
            float pre[4];
            #pragma unroll
            for (int q = 0; q < 4; ++q)
                pre[q] = G[w][j + 64 * q] + fmaf(xt, wih0v[q], bias0v[q]);
            float iv = sigm(pre[0]), fv = sigm(pre[1]);
            float gv = tanh_fast(pre[2]), ov = sigm(pre[3]);
            c1 = fmaf(fv, c1, iv * gv);
            float h1 = ov * tanh_fast(c1);
            _Float16 hh = (_Float16)h1;
            h1h[w][j] = hh;
            h1l[w][j] = (_Float16)(h1 - (float)hh);
        }
        __syncthreads();                                        // B: h1(t) ready

        // ---- B-frags for h1(t) (also reused by next L0) ----
        #pragma unroll
        for (int ks = 0; ks < 2; ++ks) {
            bh1h[ks] = *(const h8*)&h1h[cc][ks * 32 + g4 * 8];
            bh1l[ks] = *(const h8*)&h1l[cc][ks * 32 + g4 * 8];
        }

        // ---- L1 MFMA: G1 = Wih1*h1(t) + Whh1*h2(t-1), 12 mfma per tile ----
        {
            f4 acc[4];
            #pragma unroll
            for (int tt = 0; tt < 4; ++tt) acc[tt] = MFMA16(aL1[tt][0][0], bh1h[0], z4);
            #pragma unroll
            for (int tt = 0; tt < 4; ++tt) acc[tt] = MFMA16(aL1[tt][0][1], bh1h[0], acc[tt]);
            #pragma unroll
            for (int tt = 0; tt < 4; ++tt) acc[tt] = MFMA16(aL1[tt][0][0], bh1l[0], acc[tt]);
            #pragma unroll
            for (int tt = 0; tt < 4; ++tt) acc[tt] = MFMA16(aL1[tt][1][0], bh1h[1], acc[tt]);
            #pragma unroll
            for (int tt = 0; tt < 4; ++tt) acc[tt] = MFMA16(aL1[tt][1][1], bh1h[1], acc[tt]);
            #pragma unroll
            for (int tt = 0; tt < 4; ++tt) acc[tt] = MFMA16(aL1[tt][1][0], bh1l[1], acc[tt]);
            #pragma unroll
            for (int tt = 0; tt < 4; ++tt) acc[tt] = MFMA16(aL1[tt][2][0], bh2h[0], acc[tt]);
            #pragma unroll
            for (int tt = 0; tt < 4; ++tt) acc[tt] = MFMA16(aL1[tt][2][1], bh2h[0], acc[tt]);
            #pragma unroll
            for (int tt = 0; tt < 4; ++tt) acc[tt] = MFMA16(aL1[tt][2][0], bh2l[0], acc[tt]);
            #pragma unroll
            for (int tt = 0; tt < 4; ++tt) acc[tt] = MFMA16(aL1[tt][3][0], bh2h[1], acc[tt]);
            #pragma unroll
            for (int tt = 0; tt < 4; ++tt) acc[tt] = MFMA16(aL1[tt][3][1], bh2h[1], acc[tt]);
            #pragma unroll
            for (int tt = 0; tt < 4; ++tt) acc[tt] = MFMA16(aL1[tt][3][0], bh2l[1], acc[tt]);
            if (r16 < NB) {
                #pragma unroll
                for (int tt = 0; tt < 4; ++tt)
                    *(f4*)&G[r16][64 * w + tt * 16 + g4 * 4] = acc[tt];
            }
        }
        __syncthreads();                                        // C: preact1 ready

        // ---- cell 1 ----
        {
            float pre[4];
            #pragma unroll
            for (int q = 0; q < 4; ++q)
                pre[q] = G[w][j + 64 * q] + bias1v[q];
            float iv = sigm(pre[0]), fv = sigm(pre[1]);
            float gv = tanh_fast(pre[2]), ov = sigm(pre[3]);
            c2 = fmaf(fv, c2, iv * gv);
            float h2 = ov * tanh_fast(c2);
            _Float16 hh = (_Float16)h2;
            h2h[w][j] = hh;
            h2l[w][j] = (_Float16)(h2 - (float)hh);
            if (t == SEQT - 1) h2f[w][j] = h2;
        }
        if ((t & 63) == 63 && t < SEQT - 1)
            xl[tid >> 2][tid & 3] = x[(size_t)(B0 + (tid & 3)) * SEQT + (t + 1) + (tid >> 2)];
        __syncthreads();                                        // D: h2(t), x ready
    }

    // ---------------- FC head: wave w -> batch w ----------------
    {
        float z = 0.0f;
        if (j < 32) {
            float acc = fc1_b[j];
            const float4* hv = (const float4*)h2f[w];
            const float4* wv = (const float4*)(fc1_w + j * HID);
            #pragma unroll
            for (int q = 0; q < 16; ++q) {
                float4 h = hv[q], ww = wv[q];
                acc = fmaf(h.x, ww.x, acc); acc = fmaf(h.y, ww.y, acc);
                acc = fmaf(h.z, ww.z, acc); acc = fmaf(h.w, ww.w, acc);
            }
            z = fmaxf(acc, 0.0f) * fc2_w[j];
        }
        #pragma unroll
        for (int off = 32; off > 0; off >>= 1) z += __shfl_xor(z, off);
        if (j == 0) out[B0 + w] = z + fc2_b[0];
    }
}

extern "C" void kernel_launch(void* const* d_in, const int* in_sizes, int n_in,
                              void* d_out, int out_size, void* d_ws, size_t ws_size,
                              hipStream_t stream) {
    const float* x     = (const float*)d_in[0];
    const float* W_ih0 = (const float*)d_in[1];
    const float* W_hh0 = (const float*)d_in[2];
    const float* b_ih0 = (const float*)d_in[3];
    const float* b_hh0 = (const float*)d_in[4];
    const float* W_ih1 = (const float*)d_in[5];
    const float* W_hh1 = (const float*)d_in[6];
    const float* b_ih1 = (const float*)d_in[7];
    const float* b_hh1 = (const float*)d_in[8];
    const float* fc1_w = (const float*)d_in[9];
    const float* fc1_b = (const float*)d_in[10];
    const float* fc2_w = (const float*)d_in[11];
    const float* fc2_b = (const float*)d_in[12];
    float* out = (float*)d_out;

    const int batch = in_sizes[0] / SEQT;   // 1024
    const int nblk  = batch / NB;           // 256 blocks, 1 per CU
    dim3 grid(nblk), block(256);
    hipLaunchKernelGGL(lstm2_mfma, grid, block, 0, stream,
                       x, W_ih0, W_hh0, b_ih0, b_hh0,
                       W_ih1, W_hh1, b_ih1, b_hh1,
                       fc1_w, fc1_b, fc2_w, fc2_b, out, nblk);
}

// Round 7
// 1173.996 us; speedup vs baseline: 1.9226x; 1.0216x over previous
//
#include <hip/hip_runtime.h>

#define HID  64
#define SEQT 1024
#define NB   4

typedef _Float16 h8 __attribute__((ext_vector_type(8)));
typedef float    f4 __attribute__((ext_vector_type(4)));

__device__ __forceinline__ float rcpf(float x){ return __builtin_amdgcn_rcpf(x); }
__device__ __forceinline__ float sigm(float x){ return rcpf(1.0f + __expf(-x)); }
__device__ __forceinline__ float tanh_fast(float x){
    // 1 - 2/(e^{2x}+1); correct saturation at +-inf
    return 1.0f - 2.0f * rcpf(__expf(2.0f * x) + 1.0f);
}

#define MFMA16(A,B,C) __builtin_amdgcn_mfma_f32_16x16x32_f16((A),(B),(C),0,0,0)

// split fp32 -> f16 hi + f16 lo (exact residual; 3-term product ~2^-24 rel)
__device__ __forceinline__ void split8(const float* __restrict__ p, h8& hi, h8& lo) {
    float4 u = *(const float4*)p;
    float4 v = *(const float4*)(p + 4);
    float vv[8] = {u.x, u.y, u.z, u.w, v.x, v.y, v.z, v.w};
    #pragma unroll
    for (int e = 0; e < 8; ++e) {
        _Float16 h = (_Float16)vv[e];
        hi[e] = h;
        lo[e] = (_Float16)(vv[e] - (float)h);
    }
}

// Round-6 MFMA kernel with L0/L1 software-pipelined into ONE MFMA phase and
// ONE cell phase per iter (2 barriers/step instead of 4):
//   iter t: MFMA computes G0(t) = Whh0*h1(t-1)  and  G1(t-1) = Wih1*h1(t-1)
//           + Whh1*h2(t-2)   [8 independent acc chains, 72 MFMA issue-bound]
//           -> barrier -> cell0 makes h1(t), cell1 makes h2(t-1) -> barrier.
// h1/h2 double-buffered in LDS: state of step s lives in buffer s&1, so the
// phase that reads step s-1 never touches the buffer being written.
// xt is read in the MFMA phase (barrier-separated from the x-tile refill that
// shares the cell phase). All fragment mappings identical to round 6
// (verified absmax=0): A/B use the same k-formula; C/D col=lane&15,
// row=(lane>>4)*4+reg.
__global__ __launch_bounds__(256, 1)
void lstm2_pl(const float* __restrict__ x,
              const float* __restrict__ W_ih0, const float* __restrict__ W_hh0,
              const float* __restrict__ b_ih0, const float* __restrict__ b_hh0,
              const float* __restrict__ W_ih1, const float* __restrict__ W_hh1,
              const float* __restrict__ b_ih1, const float* __restrict__ b_hh1,
              const float* __restrict__ fc1_w, const float* __restrict__ fc1_b,
              const float* __restrict__ fc2_w, const float* __restrict__ fc2_b,
              float* __restrict__ out, int nblk)
{
    const int blk = blockIdx.x;
    if (blk >= nblk) return;
    const int tid = threadIdx.x;
    const int w   = tid >> 6;          // wave id; == batch for cell phase
    const int l   = tid & 63;          // lane
    const int r16 = l & 15;            // A row / D col select
    const int g4  = l >> 4;            // k-subgroup
    const int cc  = r16 & 3;           // broadcast col for B (pad lanes -> col&3)
    const int j   = l;                 // cell unit
    const int B0  = blk * NB;

    // ---------------- LDS ----------------
    // h state: [buf][batch col][k halves], stride 80 halves = 160 B
    __shared__ __align__(16) _Float16 h1h[2][NB][80], h1l[2][NB][80];
    __shared__ __align__(16) _Float16 h2h[2][NB][80], h2l[2][NB][80];
    __shared__ __align__(16) float G0[NB][260];
    __shared__ __align__(16) float G1[NB][260];
    __shared__ __align__(16) float xl[64][8];     // x chunk [t&63][batch]
    __shared__ __align__(16) float h2f[NB][64];   // final h2 fp32 for FC head

    // ---------------- A-fragments: weights, hi/lo f16 ----------------
    h8 aL0[4][2][2];     // [tile][ks][hi/lo]  W_hh0
    h8 aL1[4][4][2];     // ks 0,1: W_ih1 ; ks 2,3: W_hh1
    #pragma unroll
    for (int tt = 0; tt < 4; ++tt) {
        const int row = 64 * w + tt * 16 + r16;
        #pragma unroll
        for (int ks = 0; ks < 2; ++ks)
            split8(W_hh0 + row * HID + ks * 32 + g4 * 8, aL0[tt][ks][0], aL0[tt][ks][1]);
        #pragma unroll
        for (int ks = 0; ks < 2; ++ks)
            split8(W_ih1 + row * HID + ks * 32 + g4 * 8, aL1[tt][ks][0], aL1[tt][ks][1]);
        #pragma unroll
        for (int ks = 0; ks < 2; ++ks)
            split8(W_hh1 + row * HID + ks * 32 + g4 * 8, aL1[tt][2 + ks][0], aL1[tt][2 + ks][1]);
    }

    // ---------------- cell-thread constants ----------------
    float bias0v[4], bias1v[4], wih0v[4];
    #pragma unroll
    for (int q = 0; q < 4; ++q) {
        const int row = j + 64 * q;
        bias0v[q] = b_ih0[row] + b_hh0[row];
        bias1v[q] = b_ih1[row] + b_hh1[row];
        wih0v[q]  = W_ih0[row];
    }

    // ---------------- init LDS (zero both h buffers) ----------------
    for (int q = tid; q < 2 * NB * 80 / 2; q += 256) {   // 320 ints per array
        ((int*)h1h)[q] = 0; ((int*)h1l)[q] = 0;
        ((int*)h2h)[q] = 0; ((int*)h2l)[q] = 0;
    }
    xl[tid >> 2][tid & 3] = x[(size_t)(B0 + (tid & 3)) * SEQT + (tid >> 2)];
    float c1 = 0.0f, c2 = 0.0f;
    __syncthreads();

    const f4 z4 = {0.f, 0.f, 0.f, 0.f};

    // iter t: L0 emits step t (t<SEQT), L1 emits step t-1 (t>=1)
    #pragma unroll 1
    for (int t = 0; t <= SEQT; ++t) {
        const int rb1 = (t + 1) & 1;   // buf of h1(t-1)
        const int wb1 = t & 1;         // buf for h1(t)
        const int rb2 = t & 1;         // buf of h2(t-2)
        const int wb2 = (t + 1) & 1;   // buf for h2(t-1)

        // ---- B-fragments (shared by L0 and L1) ----
        h8 bh1hF[2], bh1lF[2], bh2hF[2], bh2lF[2];
        #pragma unroll
        for (int ks = 0; ks < 2; ++ks) {
            bh1hF[ks] = *(const h8*)&h1h[rb1][cc][ks * 32 + g4 * 8];
            bh1lF[ks] = *(const h8*)&h1l[rb1][cc][ks * 32 + g4 * 8];
            bh2hF[ks] = *(const h8*)&h2h[rb2][cc][ks * 32 + g4 * 8];
            bh2lF[ks] = *(const h8*)&h2l[rb2][cc][ks * 32 + g4 * 8];
        }
        // xt read here: barrier-separated from the refill in the cell phase
        const float xt = xl[t & 63][w];

        // ---- L0 MFMA: G0(t) = Whh0 * h1(t-1), 4 chains x 6 ----
        if (t < SEQT) {
            f4 acc[4];
            #pragma unroll
            for (int tt = 0; tt < 4; ++tt) acc[tt] = MFMA16(aL0[tt][0][0], bh1hF[0], z4);
            #pragma unroll
            for (int tt = 0; tt < 4; ++tt) acc[tt] = MFMA16(aL0[tt][0][1], bh1hF[0], acc[tt]);
            #pragma unroll
            for (int tt = 0; tt < 4; ++tt) acc[tt] = MFMA16(aL0[tt][0][0], bh1lF[0], acc[tt]);
            #pragma unroll
            for (int tt = 0; tt < 4; ++tt) acc[tt] = MFMA16(aL0[tt][1][0], bh1hF[1], acc[tt]);
            #pragma unroll
            for (int tt = 0; tt < 4; ++tt) acc[tt] = MFMA16(aL0[tt][1][1], bh1hF[1], acc[tt]);
            #pragma unroll
            for (int tt = 0; tt < 4; ++tt) acc[tt] = MFMA16(aL0[tt][1][0], bh1lF[1], acc[tt]);
            if (r16 < NB) {
                #pragma unroll
                for (int tt = 0; tt < 4; ++tt)
                    *(f4*)&G0[r16][64 * w + tt * 16 + g4 * 4] = acc[tt];
            }
        }

        // ---- L1 MFMA: G1(t-1) = Wih1*h1(t-1) + Whh1*h2(t-2), 4 chains x 12 ----
        if (t >= 1) {
            f4 acc[4];
            #pragma unroll
            for (int tt = 0; tt < 4; ++tt) acc[tt] = MFMA16(aL1[tt][0][0], bh1hF[0], z4);
            #pragma unroll
            for (int tt = 0; tt < 4; ++tt) acc[tt] = MFMA16(aL1[tt][0][1], bh1hF[0], acc[tt]);
            #pragma unroll
            for (int tt = 0; tt < 4; ++tt) acc[tt] = MFMA16(aL1[tt][0][0], bh1lF[0], acc[tt]);
            #pragma unroll
            for (int tt = 0; tt < 4; ++tt) acc[tt] = MFMA16(aL1[tt][1][0], bh1hF[1], acc[tt]);
            #pragma unroll
            for (int tt = 0; tt < 4; ++tt) acc[tt] = MFMA16(aL1[tt][1][1], bh1hF[1], acc[tt]);
            #pragma unroll
            for (int tt = 0; tt < 4; ++tt) acc[tt] = MFMA16(aL1[tt][1][0], bh1lF[1], acc[tt]);
            #pragma unroll
            for (int tt = 0; tt < 4; ++tt) acc[tt] = MFMA16(aL1[tt][2][0], bh2hF[0], acc[tt]);
            #pragma unroll
            for (int tt = 0; tt < 4; ++tt) acc[tt] = MFMA16(aL1[tt][2][1], bh2hF[0], acc[tt]);
            #pragma unroll
            for (int tt = 0; tt < 4; ++tt) acc[tt] = MFMA16(aL1[tt][2][0], bh2lF[0], acc[tt]);
            #pragma unroll
            for (int tt = 0; tt < 4; ++tt) acc[tt] = MFMA16(aL1[tt][3][0], bh2hF[1], acc[tt]);
            #pragma unroll
            for (int tt = 0; tt < 4; ++tt) acc[tt] = MFMA16(aL1[tt][3][1], bh2hF[1], acc[tt]);
            #pragma unroll
            for (int tt = 0; tt < 4; ++tt) acc[tt] = MFMA16(aL1[tt][3][0], bh2lF[1], acc[tt]);
            if (r16 < NB) {
                #pragma unroll
                for (int tt = 0; tt < 4; ++tt)
                    *(f4*)&G1[r16][64 * w + tt * 16 + g4 * 4] = acc[tt];
            }
        }
        __syncthreads();                           // G0(t), G1(t-1) ready

        // ---- cell phase: thread (unit j, batch w), both layers ----
        if (t < SEQT) {                            // cell0 -> h1(t)
            float pre[4];
            #pragma unroll
            for (int q = 0; q < 4; ++q)
                pre[q] = G0[w][j + 64 * q] + fmaf(xt, wih0v[q], bias0v[q]);
            float iv = sigm(pre[0]), fv = sigm(pre[1]);
            float gv = tanh_fast(pre[2]), ov = sigm(pre[3]);
            c1 = fmaf(fv, c1, iv * gv);
            float h1 = ov * tanh_fast(c1);
            _Float16 hh = (_Float16)h1;
            h1h[wb1][w][j] = hh;
            h1l[wb1][w][j] = (_Float16)(h1 - (float)hh);
        }
        if (t >= 1) {                              // cell1 -> h2(t-1)
            float pre[4];
            #pragma unroll
            for (int q = 0; q < 4; ++q)
                pre[q] = G1[w][j + 64 * q] + bias1v[q];
            float iv = sigm(pre[0]), fv = sigm(pre[1]);
            float gv = tanh_fast(pre[2]), ov = sigm(pre[3]);
            c2 = fmaf(fv, c2, iv * gv);
            float h2 = ov * tanh_fast(c2);
            _Float16 hh = (_Float16)h2;
            h2h[wb2][w][j] = hh;
            h2l[wb2][w][j] = (_Float16)(h2 - (float)hh);
            if (t == SEQT) h2f[w][j] = h2;
        }
        if ((t & 63) == 63 && t < SEQT - 1)        // refill x tile for t+1..t+64
            xl[tid >> 2][tid & 3] = x[(size_t)(B0 + (tid & 3)) * SEQT + (t + 1) + (tid >> 2)];
        __syncthreads();                           // h1(t), h2(t-1), x ready
    }

    // ---------------- FC head: wave w -> batch w ----------------
    {
        float z = 0.0f;
        if (j < 32) {
            float acc = fc1_b[j];
            const float4* hv = (const float4*)h2f[w];
            const float4* wv = (const float4*)(fc1_w + j * HID);
            #pragma unroll
            for (int q = 0; q < 16; ++q) {
                float4 h = hv[q], ww = wv[q];
                acc = fmaf(h.x, ww.x, acc); acc = fmaf(h.y, ww.y, acc);
                acc = fmaf(h.z, ww.z, acc); acc = fmaf(h.w, ww.w, acc);
            }
            z = fmaxf(acc, 0.0f) * fc2_w[j];
        }
        #pragma unroll
        for (int off = 32; off > 0; off >>= 1) z += __shfl_xor(z, off);
        if (j == 0) out[B0 + w] = z + fc2_b[0];
    }
}

extern "C" void kernel_launch(void* const* d_in, const int* in_sizes, int n_in,
                              void* d_out, int out_size, void* d_ws, size_t ws_size,
                              hipStream_t stream) {
    const float* x     = (const float*)d_in[0];
    const float* W_ih0 = (const float*)d_in[1];
    const float* W_hh0 = (const float*)d_in[2];
    const float* b_ih0 = (const float*)d_in[3];
    const float* b_hh0 = (const float*)d_in[4];
    const float* W_ih1 = (const float*)d_in[5];
    const float* W_hh1 = (const float*)d_in[6];
    const float* b_ih1 = (const float*)d_in[7];
    const float* b_hh1 = (const float*)d_in[8];
    const float* fc1_w = (const float*)d_in[9];
    const float* fc1_b = (const float*)d_in[10];
    const float* fc2_w = (const float*)d_in[11];
    const float* fc2_b = (const float*)d_in[12];
    float* out = (float*)d_out;

    const int batch = in_sizes[0] / SEQT;   // 1024
    const int nblk  = batch / NB;           // 256 blocks, 1 per CU
    dim3 grid(nblk), block(256);
    hipLaunchKernelGGL(lstm2_pl, grid, block, 0, stream,
                       x, W_ih0, W_hh0, b_ih0, b_hh0,
                       W_ih1, W_hh1, b_ih1, b_hh1,
                       fc1_w, fc1_b, fc2_w, fc2_b, out, nblk);
}